// Round 2
// baseline (273.848 us; speedup 1.0000x reference)
//
#include <hip/hip_runtime.h>

// Reference collapses to an all-zeros output:
//   probs = one-hot at index 0; gathered = probs[:, {1,2,4,...,128}] == 0;
//   p1 = p2 = 0; 0/(0+eps) = 0; p1 @ p2.T = zeros(8192, 8192) float32.
// So the only work is zero-filling d_out (256 MiB), which the harness
// poisons to 0xAA before every timed replay. Pure write-BW bound.

typedef float vfloat4 __attribute__((ext_vector_type(4)));

__global__ __launch_bounds__(256) void pqk_zero_kernel(vfloat4* __restrict__ out,
                                                       long long n4) {
    long long i = (long long)blockIdx.x * blockDim.x + threadIdx.x;
    long long stride = (long long)gridDim.x * blockDim.x;
    const vfloat4 z = {0.f, 0.f, 0.f, 0.f};
    for (; i < n4; i += stride) {
        __builtin_nontemporal_store(z, &out[i]);
    }
}

extern "C" void kernel_launch(void* const* d_in, const int* in_sizes, int n_in,
                              void* d_out, int out_size, void* d_ws, size_t ws_size,
                              hipStream_t stream) {
    // out_size = 8192*8192 floats; divisible by 4.
    long long n4 = (long long)out_size / 4;
    const int block = 256;
    // 8192 blocks -> 2M threads, 8 float4 stores each (grid-stride).
    int grid = 8192;
    pqk_zero_kernel<<<grid, block, 0, stream>>>((vfloat4*)d_out, n4);
}